// Round 1
// baseline (986.366 us; speedup 1.0000x reference)
//
#include <hip/hip_runtime.h>

#define H_ 1024
#define B_ 8192
#define E_ 16
#define D_ 2
#define BM 128
#define BN 128
#define BK 32

typedef _Float16 f16;
typedef _Float16 f16x4 __attribute__((ext_vector_type(4)));
typedef _Float16 f16x8 __attribute__((ext_vector_type(8)));
typedef float    f32x4 __attribute__((ext_vector_type(4)));

__device__ __forceinline__ void gload16(const void* g, void* l) {
  __builtin_amdgcn_global_load_lds((const __attribute__((address_space(1))) void*)g,
                                   (__attribute__((address_space(3))) void*)l, 16, 0, 0);
}

// f32 -> (f16 hi, f16 lo) planes. lo = x - (float)hi, so hi+lo ~ x to ~2^-22 rel.
__global__ void split_kernel(const float* __restrict__ s, f16* __restrict__ hp,
                             f16* __restrict__ lp, int n) {
  const int stride = gridDim.x * blockDim.x * 4;
  for (int i = (blockIdx.x * blockDim.x + threadIdx.x) * 4; i < n; i += stride) {
    float4 v = *(const float4*)(s + i);
    f16 h0 = (f16)v.x, h1 = (f16)v.y, h2 = (f16)v.z, h3 = (f16)v.w;
    f16 l0 = (f16)(v.x - (float)h0), l1 = (f16)(v.y - (float)h1);
    f16 l2 = (f16)(v.z - (float)h2), l3 = (f16)(v.w - (float)h3);
    *(f16x4*)(hp + i) = (f16x4){h0, h1, h2, h3};
    *(f16x4*)(lp + i) = (f16x4){l0, l1, l2, l3};
  }
}

// one wave per token: f32 gate logits, top-2 (jax tie-break: lower index first),
// softmax over the 2 selected, scatter into per-expert token lists.
__global__ void gate_topk(const float* __restrict__ x, const float* __restrict__ gw,
                          const float* __restrict__ gb, int* __restrict__ lists,
                          float* __restrict__ wlist, int* __restrict__ counts) {
  const int token = blockIdx.x * 4 + (threadIdx.x >> 6);
  const int lane = threadIdx.x & 63;
  const float4* xr = (const float4*)(x + (long)token * H_);
  float acc[E_];
#pragma unroll
  for (int e = 0; e < E_; ++e) acc[e] = 0.f;
#pragma unroll
  for (int i0 = 0; i0 < H_ / 4; i0 += 64) {
    float4 xv = xr[i0 + lane];
#pragma unroll
    for (int e = 0; e < E_; ++e) {
      float4 gv = ((const float4*)(gw + e * H_))[i0 + lane];
      acc[e] = fmaf(xv.x, gv.x, fmaf(xv.y, gv.y, fmaf(xv.z, gv.z, fmaf(xv.w, gv.w, acc[e]))));
    }
  }
#pragma unroll
  for (int off = 32; off; off >>= 1) {
#pragma unroll
    for (int e = 0; e < E_; ++e) acc[e] += __shfl_xor(acc[e], off, 64);
  }
  if (lane == 0) {
    float g[E_];
#pragma unroll
    for (int e = 0; e < E_; ++e) g[e] = acc[e] + gb[e];
    int i0 = 0; float v0 = g[0];
#pragma unroll
    for (int e = 1; e < E_; ++e) if (g[e] > v0) { v0 = g[e]; i0 = e; }
    int i1 = -1; float v1 = -3.4e38f;
#pragma unroll
    for (int e = 0; e < E_; ++e) if (e != i0 && g[e] > v1) { v1 = g[e]; i1 = e; }
    float t = expf(v1 - v0);
    float s = 1.f / (1.f + t);
    int p0 = atomicAdd(&counts[i0], 1);
    lists[i0 * B_ + p0] = token; wlist[i0 * B_ + p0] = s;
    int p1 = atomicAdd(&counts[i1], 1);
    lists[i1 * B_ + p1] = token; wlist[i1 * B_ + p1] = t * s;
  }
}

// Grouped GEMM over (expert, token-tile, out-tile). Split-f16: y = xh*wh + xh*wl + xl*wh.
// LDS planes Ah/Al/Bh/Bl each [128 rows][32 k] f16 = 8KB, slot-swizzled:
//   element (r,k) at byte r*64 + (((k>>3)+(r>>1))&3)*16 + (k&7)*2
// global_load_lds writes linearly (base+lane*16); source address is inverse-swizzled.
__global__ __launch_bounds__(256, 2) void expert_gemm(
    const f16* __restrict__ xh, const f16* __restrict__ xl,
    const f16* __restrict__ wh, const f16* __restrict__ wl,
    const float* __restrict__ eb, const float* __restrict__ pl,
    const float* __restrict__ pr, const float* __restrict__ pp,
    const float* __restrict__ pb, const int* __restrict__ lists,
    const float* __restrict__ wlist, const int* __restrict__ counts,
    float* __restrict__ out) {
  const int e = blockIdx.z;
  const int cnt = counts[e];
  const int mt = blockIdx.y;
  if (mt * BM >= cnt) return;
  const int nt = blockIdx.x;

  __shared__ char smem[32768 + BM * 8];
  int* tokS = (int*)(smem + 32768);
  float* wtS = (float*)(smem + 32768 + BM * 4);

  const int tid = threadIdx.x;
  const int lane = tid & 63;
  const int wave = tid >> 6;
  const int wm = wave >> 1, wn = wave & 1;

  if (tid < BM) {
    int gr = mt * BM + tid;
    int tok = 0; float wgt = 0.f;
    if (gr < cnt) { tok = lists[e * B_ + gr]; wgt = wlist[e * B_ + gr]; }
    tokS[tid] = tok; wtS[tid] = wgt;
  }
  __syncthreads();

  // staging: wave handles 16-row chunks c0=2w, c1=2w+1 of all 4 planes.
  // lane -> row r = c*16 + (lane>>2), dest slot = lane&3 which holds logical
  // k-slot ks = ((lane&3) - ((lane>>3)&3)) & 3  (inverse of the read swizzle).
  const int rl = lane >> 2;
  const int ks = ((lane & 3) - ((lane >> 3) & 3)) & 3;
  const int c0 = wave * 2, c1 = wave * 2 + 1;
  const int rA0 = c0 * 16 + rl, rA1 = c1 * 16 + rl;
  const long a0 = (long)tokS[rA0] * H_ + ks * 8;
  const long a1 = (long)tokS[rA1] * H_ + ks * 8;
  const long b0 = ((long)e * H_ + nt * BN + rA0) * H_ + ks * 8;
  const long b1 = ((long)e * H_ + nt * BN + rA1) * H_ + ks * 8;

  // fragment-read byte offsets (swizzled): row = sub*16 + (lane&15),
  // stored slot = ((lane>>4) + ((lane&15)>>1)) & 3
  const int rm = lane & 15;
  const int sl = ((((lane >> 4) + (rm >> 1)) & 3) << 4);
  int offA[4], offB[4];
#pragma unroll
  for (int m = 0; m < 4; ++m) offA[m] = (wm * 64 + m * 16 + rm) * 64 + sl;
#pragma unroll
  for (int n = 0; n < 4; ++n) offB[n] = (wn * 64 + n * 16 + rm) * 64 + sl;

  f32x4 acc[4][4] = {};

  for (int kt = 0; kt < H_; kt += BK) {
    gload16(xh + a0 + kt, smem + c0 * 1024);
    gload16(xh + a1 + kt, smem + c1 * 1024);
    gload16(xl + a0 + kt, smem + 8192 + c0 * 1024);
    gload16(xl + a1 + kt, smem + 8192 + c1 * 1024);
    gload16(wh + b0 + kt, smem + 16384 + c0 * 1024);
    gload16(wh + b1 + kt, smem + 16384 + c1 * 1024);
    gload16(wl + b0 + kt, smem + 24576 + c0 * 1024);
    gload16(wl + b1 + kt, smem + 24576 + c1 * 1024);
    __syncthreads();  // drains vmcnt -> LDS writes visible

    f16x8 Amh[4], Aml[4], Bnh[4], Bnl[4];
#pragma unroll
    for (int m = 0; m < 4; ++m) {
      Amh[m] = *(const f16x8*)(smem + offA[m]);
      Aml[m] = *(const f16x8*)(smem + 8192 + offA[m]);
    }
#pragma unroll
    for (int n = 0; n < 4; ++n) {
      Bnh[n] = *(const f16x8*)(smem + 16384 + offB[n]);
      Bnl[n] = *(const f16x8*)(smem + 24576 + offB[n]);
    }
#pragma unroll
    for (int m = 0; m < 4; ++m) {
#pragma unroll
      for (int n = 0; n < 4; ++n) {
        acc[m][n] = __builtin_amdgcn_mfma_f32_16x16x32_f16(Amh[m], Bnh[n], acc[m][n], 0, 0, 0);
        acc[m][n] = __builtin_amdgcn_mfma_f32_16x16x32_f16(Amh[m], Bnl[n], acc[m][n], 0, 0, 0);
        acc[m][n] = __builtin_amdgcn_mfma_f32_16x16x32_f16(Aml[m], Bnh[n], acc[m][n], 0, 0, 0);
      }
    }
    __syncthreads();
  }

  // epilogue: bias + custom PReLU + gate weight, atomicAdd into out (2 adds/token total)
  float ebv[4], plv[4], prv[4], ppv[4], pbv[4];
  int Ocol[4];
#pragma unroll
  for (int n = 0; n < 4; ++n) {
    int O = nt * BN + wn * 64 + n * 16 + rm;
    Ocol[n] = O;
    int idx = e * H_ + O;
    ebv[n] = eb[idx]; plv[n] = pl[idx]; prv[n] = pr[idx]; ppv[n] = pp[idx]; pbv[n] = pb[idx];
  }
  const int rbase = (lane >> 4) * 4;
#pragma unroll
  for (int m = 0; m < 4; ++m) {
#pragma unroll
    for (int j = 0; j < 4; ++j) {
      int rloc = wm * 64 + m * 16 + rbase + j;
      int gr = mt * BM + rloc;
      if (gr < cnt) {
        float wgt = wtS[rloc];
        long obase = (long)tokS[rloc] * H_;
#pragma unroll
        for (int n = 0; n < 4; ++n) {
          float y = acc[m][n][j] + ebv[n];
          float dlt = y - ppv[n];
          float act = pbv[n] + (dlt >= 0.f ? dlt * prv[n] : dlt * plv[n]);
          atomicAdd(out + obase + Ocol[n], wgt * act);
        }
      }
    }
  }
}

extern "C" void kernel_launch(void* const* d_in, const int* in_sizes, int n_in,
                              void* d_out, int out_size, void* d_ws, size_t ws_size,
                              hipStream_t stream) {
  const float* X  = (const float*)d_in[0];
  const float* GW = (const float*)d_in[1];
  const float* GB = (const float*)d_in[2];
  const float* EW = (const float*)d_in[3];
  const float* EB = (const float*)d_in[4];
  const float* PL = (const float*)d_in[5];
  const float* PR = (const float*)d_in[6];
  const float* PP = (const float*)d_in[7];
  const float* PB = (const float*)d_in[8];
  float* out = (float*)d_out;

  char* ws = (char*)d_ws;
  float* x1    = (float*)(ws);                 // 33,554,432 B (layer-0 output, f32)
  f16*   xh    = (f16*)(ws + 33554432);        // 16,777,216
  f16*   xl    = (f16*)(ws + 50331648);        // 16,777,216
  f16*   wh    = (f16*)(ws + 67108864);        // 33,554,432
  f16*   wl    = (f16*)(ws + 100663296);       // 33,554,432
  int*   lists = (int*)(ws + 134217728);       //    524,288
  float* wlist = (float*)(ws + 134742016);     //    524,288
  int*   counts= (int*)(ws + 135266304);       //         64   (total ~135.3 MB)

  for (int d = 0; d < D_; ++d) {
    const float* xin = d ? x1 : X;
    float* xout = d ? out : x1;
    hipMemsetAsync(counts, 0, 64, stream);
    hipMemsetAsync(xout, 0, (size_t)B_ * H_ * 4, stream);
    split_kernel<<<2048, 256, 0, stream>>>(xin, xh, xl, B_ * H_);
    split_kernel<<<2048, 256, 0, stream>>>(EW + (size_t)d * E_ * H_ * H_, wh, wl, E_ * H_ * H_);
    gate_topk<<<B_ / 4, 256, 0, stream>>>(xin, GW + d * E_ * H_, GB + d * E_,
                                          lists, wlist, counts);
    expert_gemm<<<dim3(H_ / BN, B_ / BM, E_), 256, 0, stream>>>(
        xh, xl, wh, wl, EB + d * E_ * H_, PL + d * E_ * H_, PR + d * E_ * H_,
        PP + d * E_ * H_, PB + d * E_ * H_, lists, wlist, counts, xout);
  }
}

// Round 2
// 638.135 us; speedup vs baseline: 1.5457x; 1.5457x over previous
//
#include <hip/hip_runtime.h>

#define H_ 1024
#define B_ 8192
#define E_ 16
#define D_ 2
#define BM 128
#define BN 128
#define BK 32

typedef _Float16 f16;
typedef _Float16 f16x4 __attribute__((ext_vector_type(4)));
typedef _Float16 f16x8 __attribute__((ext_vector_type(8)));
typedef float    f32x4 __attribute__((ext_vector_type(4)));

__device__ __forceinline__ void gload16(const void* g, void* l) {
  __builtin_amdgcn_global_load_lds((const __attribute__((address_space(1))) void*)g,
                                   (__attribute__((address_space(3))) void*)l, 16, 0, 0);
}

// f32 -> (f16 hi, f16 lo) planes. lo = x - (float)hi, so hi+lo ~ x to ~2^-22 rel.
__global__ void split_kernel(const float* __restrict__ s, f16* __restrict__ hp,
                             f16* __restrict__ lp, int n) {
  const int stride = gridDim.x * blockDim.x * 4;
  for (int i = (blockIdx.x * blockDim.x + threadIdx.x) * 4; i < n; i += stride) {
    float4 v = *(const float4*)(s + i);
    f16 h0 = (f16)v.x, h1 = (f16)v.y, h2 = (f16)v.z, h3 = (f16)v.w;
    f16 l0 = (f16)(v.x - (float)h0), l1 = (f16)(v.y - (float)h1);
    f16 l2 = (f16)(v.z - (float)h2), l3 = (f16)(v.w - (float)h3);
    *(f16x4*)(hp + i) = (f16x4){h0, h1, h2, h3};
    *(f16x4*)(lp + i) = (f16x4){l0, l1, l2, l3};
  }
}

// one wave per token: f32 gate logits, top-2 (strict > keeps lower index on ties,
// matching jax.lax.top_k), softmax over the 2 selected. NO atomics — results go
// to token-indexed arrays; routing scatter is a separate aggregated kernel.
__global__ void gate_kernel(const float* __restrict__ x, const float* __restrict__ gw,
                            const float* __restrict__ gb, int2* __restrict__ tok_e,
                            float2* __restrict__ tok_w) {
  const int token = blockIdx.x * 4 + (threadIdx.x >> 6);
  const int lane = threadIdx.x & 63;
  const float4* xr = (const float4*)(x + (long)token * H_);
  float acc[E_];
#pragma unroll
  for (int e = 0; e < E_; ++e) acc[e] = 0.f;
#pragma unroll
  for (int i0 = 0; i0 < H_ / 4; i0 += 64) {
    float4 xv = xr[i0 + lane];
#pragma unroll
    for (int e = 0; e < E_; ++e) {
      float4 gv = ((const float4*)(gw + e * H_))[i0 + lane];
      acc[e] = fmaf(xv.x, gv.x, fmaf(xv.y, gv.y, fmaf(xv.z, gv.z, fmaf(xv.w, gv.w, acc[e]))));
    }
  }
#pragma unroll
  for (int off = 32; off; off >>= 1) {
#pragma unroll
    for (int e = 0; e < E_; ++e) acc[e] += __shfl_xor(acc[e], off, 64);
  }
  if (lane == 0) {
    float g[E_];
#pragma unroll
    for (int e = 0; e < E_; ++e) g[e] = acc[e] + gb[e];
    int i0 = 0; float v0 = g[0];
#pragma unroll
    for (int e = 1; e < E_; ++e) if (g[e] > v0) { v0 = g[e]; i0 = e; }
    int i1 = -1; float v1 = -3.4e38f;
#pragma unroll
    for (int e = 0; e < E_; ++e) if (e != i0 && g[e] > v1) { v1 = g[e]; i1 = e; }
    float t = expf(v1 - v0);
    float s = 1.f / (1.f + t);
    tok_e[token] = (int2){i0, i1};
    tok_w[token] = (float2){s, t * s};
  }
}

// 256 tokens per block: LDS histogram -> one global atomicAdd per (block,expert)
// (512 total, vs 16384 contended single-line atomics before) -> scatter.
__global__ void route_kernel(const int2* __restrict__ tok_e, const float2* __restrict__ tok_w,
                             int* __restrict__ lists, float* __restrict__ wlist,
                             int* __restrict__ counts) {
  __shared__ int cnt[E_];
  __shared__ int base[E_];
  const int tid = threadIdx.x;
  const int token = blockIdx.x * 256 + tid;
  if (tid < E_) cnt[tid] = 0;
  __syncthreads();
  int2 e = tok_e[token];
  float2 w = tok_w[token];
  int p0 = atomicAdd(&cnt[e.x], 1);
  int p1 = atomicAdd(&cnt[e.y], 1);
  __syncthreads();
  if (tid < E_) base[tid] = atomicAdd(&counts[tid], cnt[tid]);
  __syncthreads();
  int o0 = e.x * B_ + base[e.x] + p0;
  lists[o0] = token; wlist[o0] = w.x;
  int o1 = e.y * B_ + base[e.y] + p1;
  lists[o1] = token; wlist[o1] = w.y;
}

// Grouped GEMM over (expert, token-tile, out-tile). Split-f16: y = xh*wh + xh*wl + xl*wh.
// LDS planes Ah/Al/Bh/Bl each [128 rows][32 k] f16 = 8KB, slot-swizzled:
//   element (r,k) at byte r*64 + (((k>>3)+(r>>1))&3)*16 + (k&7)*2
// global_load_lds writes linearly (base+lane*16); source address is inverse-swizzled.
__global__ __launch_bounds__(256, 2) void expert_gemm(
    const f16* __restrict__ xh, const f16* __restrict__ xl,
    const f16* __restrict__ wh, const f16* __restrict__ wl,
    const float* __restrict__ eb, const float* __restrict__ pl,
    const float* __restrict__ pr, const float* __restrict__ pp,
    const float* __restrict__ pb, const int* __restrict__ lists,
    const float* __restrict__ wlist, const int* __restrict__ counts,
    float* __restrict__ out) {
  const int e = blockIdx.z;
  const int cnt = counts[e];
  const int mt = blockIdx.y;
  if (mt * BM >= cnt) return;
  const int nt = blockIdx.x;

  __shared__ char smem[32768 + BM * 8];
  int* tokS = (int*)(smem + 32768);
  float* wtS = (float*)(smem + 32768 + BM * 4);

  const int tid = threadIdx.x;
  const int lane = tid & 63;
  const int wave = tid >> 6;
  const int wm = wave >> 1, wn = wave & 1;

  if (tid < BM) {
    int gr = mt * BM + tid;
    int tok = 0; float wgt = 0.f;
    if (gr < cnt) { tok = lists[e * B_ + gr]; wgt = wlist[e * B_ + gr]; }
    tokS[tid] = tok; wtS[tid] = wgt;
  }
  __syncthreads();

  // staging: wave handles 16-row chunks c0=2w, c1=2w+1 of all 4 planes.
  // lane -> row r = c*16 + (lane>>2), dest slot = lane&3 which holds logical
  // k-slot ks = ((lane&3) - ((lane>>3)&3)) & 3  (inverse of the read swizzle).
  const int rl = lane >> 2;
  const int ks = ((lane & 3) - ((lane >> 3) & 3)) & 3;
  const int c0 = wave * 2, c1 = wave * 2 + 1;
  const int rA0 = c0 * 16 + rl, rA1 = c1 * 16 + rl;
  const long a0 = (long)tokS[rA0] * H_ + ks * 8;
  const long a1 = (long)tokS[rA1] * H_ + ks * 8;
  const long b0 = ((long)e * H_ + nt * BN + rA0) * H_ + ks * 8;
  const long b1 = ((long)e * H_ + nt * BN + rA1) * H_ + ks * 8;

  // fragment-read byte offsets (swizzled): row = sub*16 + (lane&15),
  // stored slot = ((lane>>4) + ((lane&15)>>1)) & 3
  const int rm = lane & 15;
  const int sl = ((((lane >> 4) + (rm >> 1)) & 3) << 4);
  int offA[4], offB[4];
#pragma unroll
  for (int m = 0; m < 4; ++m) offA[m] = (wm * 64 + m * 16 + rm) * 64 + sl;
#pragma unroll
  for (int n = 0; n < 4; ++n) offB[n] = (wn * 64 + n * 16 + rm) * 64 + sl;

  f32x4 acc[4][4] = {};

  for (int kt = 0; kt < H_; kt += BK) {
    gload16(xh + a0 + kt, smem + c0 * 1024);
    gload16(xh + a1 + kt, smem + c1 * 1024);
    gload16(xl + a0 + kt, smem + 8192 + c0 * 1024);
    gload16(xl + a1 + kt, smem + 8192 + c1 * 1024);
    gload16(wh + b0 + kt, smem + 16384 + c0 * 1024);
    gload16(wh + b1 + kt, smem + 16384 + c1 * 1024);
    gload16(wl + b0 + kt, smem + 24576 + c0 * 1024);
    gload16(wl + b1 + kt, smem + 24576 + c1 * 1024);
    __syncthreads();  // drains vmcnt -> LDS writes visible

    f16x8 Amh[4], Aml[4], Bnh[4], Bnl[4];
#pragma unroll
    for (int m = 0; m < 4; ++m) {
      Amh[m] = *(const f16x8*)(smem + offA[m]);
      Aml[m] = *(const f16x8*)(smem + 8192 + offA[m]);
    }
#pragma unroll
    for (int n = 0; n < 4; ++n) {
      Bnh[n] = *(const f16x8*)(smem + 16384 + offB[n]);
      Bnl[n] = *(const f16x8*)(smem + 24576 + offB[n]);
    }
#pragma unroll
    for (int m = 0; m < 4; ++m) {
#pragma unroll
      for (int n = 0; n < 4; ++n) {
        acc[m][n] = __builtin_amdgcn_mfma_f32_16x16x32_f16(Amh[m], Bnh[n], acc[m][n], 0, 0, 0);
        acc[m][n] = __builtin_amdgcn_mfma_f32_16x16x32_f16(Amh[m], Bnl[n], acc[m][n], 0, 0, 0);
        acc[m][n] = __builtin_amdgcn_mfma_f32_16x16x32_f16(Aml[m], Bnh[n], acc[m][n], 0, 0, 0);
      }
    }
    __syncthreads();
  }

  // epilogue: bias + custom PReLU + gate weight, atomicAdd into out (2 adds/token total)
  float ebv[4], plv[4], prv[4], ppv[4], pbv[4];
  int Ocol[4];
#pragma unroll
  for (int n = 0; n < 4; ++n) {
    int O = nt * BN + wn * 64 + n * 16 + rm;
    Ocol[n] = O;
    int idx = e * H_ + O;
    ebv[n] = eb[idx]; plv[n] = pl[idx]; prv[n] = pr[idx]; ppv[n] = pp[idx]; pbv[n] = pb[idx];
  }
  const int rbase = (lane >> 4) * 4;
#pragma unroll
  for (int m = 0; m < 4; ++m) {
#pragma unroll
    for (int j = 0; j < 4; ++j) {
      int rloc = wm * 64 + m * 16 + rbase + j;
      int gr = mt * BM + rloc;
      if (gr < cnt) {
        float wgt = wtS[rloc];
        long obase = (long)tokS[rloc] * H_;
#pragma unroll
        for (int n = 0; n < 4; ++n) {
          float y = acc[m][n][j] + ebv[n];
          float dlt = y - ppv[n];
          float act = pbv[n] + (dlt >= 0.f ? dlt * prv[n] : dlt * plv[n]);
          atomicAdd(out + obase + Ocol[n], wgt * act);
        }
      }
    }
  }
}

extern "C" void kernel_launch(void* const* d_in, const int* in_sizes, int n_in,
                              void* d_out, int out_size, void* d_ws, size_t ws_size,
                              hipStream_t stream) {
  const float* X  = (const float*)d_in[0];
  const float* GW = (const float*)d_in[1];
  const float* GB = (const float*)d_in[2];
  const float* EW = (const float*)d_in[3];
  const float* EB = (const float*)d_in[4];
  const float* PL = (const float*)d_in[5];
  const float* PR = (const float*)d_in[6];
  const float* PP = (const float*)d_in[7];
  const float* PB = (const float*)d_in[8];
  float* out = (float*)d_out;

  char* ws = (char*)d_ws;
  float* x1    = (float*)(ws);                 // 33,554,432 B (layer-0 output, f32)
  f16*   xh    = (f16*)(ws + 33554432);        // 16,777,216
  f16*   xl    = (f16*)(ws + 50331648);        // 16,777,216
  f16*   wh    = (f16*)(ws + 67108864);        // 33,554,432
  f16*   wl    = (f16*)(ws + 100663296);       // 33,554,432
  int*   lists = (int*)(ws + 134217728);       //    524,288
  float* wlist = (float*)(ws + 134742016);     //    524,288
  int*   counts= (int*)(ws + 135266304);       //         64
  int2*  tok_e = (int2*)(ws + 135266368);      //     65,536
  float2* tok_w= (float2*)(ws + 135331904);    //     65,536  (total ~135.4 MB)

  for (int d = 0; d < D_; ++d) {
    const float* xin = d ? x1 : X;
    float* xout = d ? out : x1;
    hipMemsetAsync(counts, 0, 64, stream);
    hipMemsetAsync(xout, 0, (size_t)B_ * H_ * 4, stream);
    split_kernel<<<2048, 256, 0, stream>>>(xin, xh, xl, B_ * H_);
    split_kernel<<<2048, 256, 0, stream>>>(EW + (size_t)d * E_ * H_ * H_, wh, wl, E_ * H_ * H_);
    gate_kernel<<<B_ / 4, 256, 0, stream>>>(xin, GW + d * E_ * H_, GB + d * E_,
                                            tok_e, tok_w);
    route_kernel<<<B_ / 256, 256, 0, stream>>>(tok_e, tok_w, lists, wlist, counts);
    expert_gemm<<<dim3(H_ / BN, B_ / BM, E_), 256, 0, stream>>>(
        xh, xl, wh, wl, EB + d * E_ * H_, PL + d * E_ * H_, PR + d * E_ * H_,
        PP + d * E_ * H_, PB + d * E_ * H_, lists, wlist, counts, xout);
  }
}